// Round 8
// baseline (641.935 us; speedup 1.0000x reference)
//
#include <hip/hip_runtime.h>
#include <hip/hip_bf16.h>

#define Bn 2
#define Sn 4096
#define Dn 512
#define Hn 8

typedef _Float16 f16x8 __attribute__((ext_vector_type(8)));
typedef __fp16 fp16x2 __attribute__((ext_vector_type(2)));
typedef float f32x16 __attribute__((ext_vector_type(16)));
typedef unsigned uint2v __attribute__((ext_vector_type(2)));

#if __has_builtin(__builtin_amdgcn_global_load_lds)
#define HAS_GLL 1
typedef const __attribute__((address_space(1))) unsigned int* gas1_t;
typedef __attribute__((address_space(3))) unsigned int* las3_t;
// async 16B/lane global->LDS: LDS dst = uniform base + lane*16
static __device__ __forceinline__ void ld_lds16(const void* g, void* l) {
    __builtin_amdgcn_global_load_lds((gas1_t)g, (las3_t)l, 16, 0, 0);
}
#else
#define HAS_GLL 0
#endif

// pack two f32 -> two f16 in one dword (v_cvt_pkrtz_f16_f32, 1 VALU op)
static __device__ __forceinline__ unsigned pkh(float a, float b) {
    union { fp16x2 h; unsigned u; } r;
    r.h = __builtin_amdgcn_cvt_pkrtz(a, b);
    return r.u;
}

// C-layout group pair -> A/B-fragment (K=16 shapes) via lane^32 exchange.
static __device__ __forceinline__ f16x8 xchg2(unsigned g0x, unsigned g0y,
                                              unsigned g1x, unsigned g1y, int hi) {
    union { unsigned u[4]; f16x8 v; } f;
#if __has_builtin(__builtin_amdgcn_permlane32_swap)
    uint2v rx = __builtin_amdgcn_permlane32_swap(g0x, g1x, false, false);
    uint2v ry = __builtin_amdgcn_permlane32_swap(g0y, g1y, false, false);
    f.u[0] = rx.x; f.u[1] = ry.x; f.u[2] = rx.y; f.u[3] = ry.y;
#else
    int sx = hi ? (int)g0x : (int)g1x;
    int sy = hi ? (int)g0y : (int)g1y;
    int rx = __shfl_xor(sx, 32);
    int ry = __shfl_xor(sy, 32);
    unsigned ox = hi ? g1x : g0x;
    unsigned oy = hi ? g1y : g0y;
    f.u[0] = hi ? (unsigned)rx : ox;
    f.u[1] = hi ? (unsigned)ry : oy;
    f.u[2] = hi ? ox : (unsigned)rx;
    f.u[3] = hi ? oy : (unsigned)ry;
#endif
    return f.v;
}

// ---------- unified prepass: K,V,W fp32 -> fragment-ordered f16 ----------
__global__ __launch_bounds__(256) void prep_kernel(
    const float* __restrict__ K, const float* __restrict__ V, const float* __restrict__ W,
    unsigned short* __restrict__ Kb, unsigned short* __restrict__ Vb,
    unsigned short* __restrict__ Wb) {
    const int vb = blockIdx.x;
    const int tid = threadIdx.x;
    if (vb < 1024) {
        const int kt = vb & 63, bh = vb >> 6;
        const int b = bh >> 3, h = bh & 7;
        unsigned short* dst = Kb + ((size_t)bh * 64 + kt) * 4096;
#pragma unroll
        for (int i = 0; i < 2; ++i) {
            int c = tid + i * 256;
            int f = c >> 6, ln = c & 63;
            int ktile = f >> 2, ks = f & 3;
            int row = ktile * 32 + (ln & 31);
            int dk = ks * 16 + (ln >> 5) * 8;
            const float* src = K + ((size_t)(b * Sn + kt * 64 + row)) * Dn + h * 64 + dk;
            float4 a0 = *(const float4*)src;
            float4 a1 = *(const float4*)(src + 4);
            uint4 o;
            o.x = pkh(a0.x, a0.y); o.y = pkh(a0.z, a0.w);
            o.z = pkh(a1.x, a1.y); o.w = pkh(a1.z, a1.w);
            *(uint4*)(dst + c * 8) = o;
        }
    } else if (vb < 2048) {
        const int u = vb - 1024;
        const int kt = u & 63, bh = u >> 6;
        const int b = bh >> 3, h = bh & 7;
        unsigned short* dst = Vb + ((size_t)bh * 64 + kt) * 4096;
#pragma unroll
        for (int i = 0; i < 2; ++i) {
            int c = tid + i * 256;
            int f = c >> 6, ln = c & 63;
            int dt = f >> 2, ks = f & 3;
            int dk = dt * 32 + (ln & 31);
            int key0 = ks * 16 + (ln >> 5) * 8;
            const float* src = V + ((size_t)(b * Sn + kt * 64 + key0)) * Dn + h * 64 + dk;
            uint4 o;
            o.x = pkh(src[0 * Dn], src[1 * Dn]);
            o.y = pkh(src[2 * Dn], src[3 * Dn]);
            o.z = pkh(src[4 * Dn], src[5 * Dn]);
            o.w = pkh(src[6 * Dn], src[7 * Dn]);
            *(uint4*)(dst + c * 8) = o;
        }
    } else {
        int c = (vb - 2048) * 256 + tid;
        int ln = c & 63, f = c >> 6;
        int ntile = f >> 5, ks = f & 31;
        int n = ntile * 32 + (ln & 31);
        int k0 = ks * 16 + (ln >> 5) * 8;
        uint4 o;
        o.x = pkh(W[(size_t)(k0 + 0) * Dn + n], W[(size_t)(k0 + 1) * Dn + n]);
        o.y = pkh(W[(size_t)(k0 + 2) * Dn + n], W[(size_t)(k0 + 3) * Dn + n]);
        o.z = pkh(W[(size_t)(k0 + 4) * Dn + n], W[(size_t)(k0 + 5) * Dn + n]);
        o.w = pkh(W[(size_t)(k0 + 6) * Dn + n], W[(size_t)(k0 + 7) * Dn + n]);
        *(uint4*)(Wb + c * 8) = o;
    }
}

// ---------- flash attention: 4 waves/SIMD AND 2:1 MFMA:LDS intensity ----------
// 512 thr = 8 waves = (qs in {0,1}) x (kg in 0..3). Wave (qs,kg): 64 q-rows
// (qt*128 + qs*64 ..+63) x keys [kg*1024, +1024) as 32 iters of 32-key tiles.
// Per wave-iter: 16 MFMA / 8KB LDS (2:1 - R7's proven intensity). LDS = 2buf
// x 4kg x 8KB = 64KB -> 2 blocks/CU -> 16 waves/CU = 4 waves/SIMD (R0's
// proven occupancy). R0-R7 ledger: (a) occupancy XOR (b) intensity each gave
// ~83us; this is the first structure with both. In-block 4-way kg-reduction
// (2-phase LDS epilogue, 48KB). XCD swizzle (R4): 2 bh/XCD -> Kb+Vb 2MB
// L2-resident. Per-SIMD iter-round: MFMA 2048cyc > VALU ~1600 > LDS 1024.
__global__ __launch_bounds__(512, 4) void attn_kernel(
    const float* __restrict__ Q,
    const unsigned short* __restrict__ Kb,
    const unsigned short* __restrict__ Vb,
    unsigned short* __restrict__ ObA) {   // [gmtile 256][ksg 32][lane 64][8]
    // main: [buf 2][kg 4][ K 4 frags | V dt0 2 | V dt1 2 ] = 2*4*4096 ush = 64KB
    // epilogue reuse: 12288 floats oacc partials + 384 floats l = 50688B
    __shared__ __align__(16) unsigned short KV[32768];

    // XCD-aware remap: id%8 = XCD (round-robin dispatch); same-bh blocks on one XCD
    const int id = blockIdx.x + (blockIdx.y << 5);
    const int qt = (id >> 3) & 31;
    const int bh = (id & 7) + ((id >> 8) << 3);
    const int b = bh >> 3, h = bh & 7;
    const int tid = threadIdx.x;
    const int wg = tid >> 6;
    const int kg = wg >> 1;        // key quarter 0..3
    const int qs = wg & 1;         // q-subgroup + staging role (0:K, 1:V)
    const int lane = tid & 63;
    const int q = lane & 31;
    const int hi = lane >> 5;
    const float cexp = 0.18033688f;  // (1/sqrt(64)) * log2(e), folded into Q

    // Q B-frags for two q-tiles: rows qt*128 + qs*64 + t*32 + q
    f16x8 qf0[4], qf1[4];
    {
        const float* qp0 = Q + ((size_t)(b * Sn + qt * 128 + qs * 64 + q)) * Dn + h * 64 + hi * 8;
        const float* qp1 = qp0 + (size_t)32 * Dn;
#pragma unroll
        for (int ks = 0; ks < 4; ++ks) {
            float4 a0 = *(const float4*)(qp0 + ks * 16);
            float4 a1 = *(const float4*)(qp0 + ks * 16 + 4);
            union { unsigned u[4]; f16x8 v; } f;
            f.u[0] = pkh(a0.x * cexp, a0.y * cexp);
            f.u[1] = pkh(a0.z * cexp, a0.w * cexp);
            f.u[2] = pkh(a1.x * cexp, a1.y * cexp);
            f.u[3] = pkh(a1.z * cexp, a1.w * cexp);
            qf0[ks] = f.v;
            a0 = *(const float4*)(qp1 + ks * 16);
            a1 = *(const float4*)(qp1 + ks * 16 + 4);
            f.u[0] = pkh(a0.x * cexp, a0.y * cexp);
            f.u[1] = pkh(a0.z * cexp, a0.w * cexp);
            f.u[2] = pkh(a1.x * cexp, a1.y * cexp);
            f.u[3] = pkh(a1.z * cexp, a1.w * cexp);
            qf1[ks] = f.v;
        }
    }

    f32x16 zf;
#pragma unroll
    for (int r = 0; r < 16; ++r) zf[r] = 0.f;
    f32x16 oacc[2][2];  // [q-tile t][d-tile dt]
    oacc[0][0] = zf; oacc[0][1] = zf; oacc[1][0] = zf; oacc[1][1] = zf;
    float l0_ = 0.f, l1_ = 0.f;

    const size_t bhbase = (size_t)bh * 64 * 4096;  // ushorts: 64 tiles x 8 frags x 512

    // stream kg, iter it covers keys kg*1024 + it*32 .. +31:
    // prep tile t64 = kg*16 + (it>>1); lo/hi half = it&1.
    // K frags (32 keys): t64 frags lohi*4 .. +3 (contiguous 4KB).
    // V frags: dt0 -> {lohi*2, lohi*2+1}, dt1 -> {4+lohi*2, 4+lohi*2+1}.
#if HAS_GLL
#define STAGE(itx, bb) { \
    const int t64 = kg * 16 + ((itx) >> 1); \
    const int lohi = (itx) & 1; \
    unsigned short* dst = &KV[(bb) * 16384 + kg * 4096]; \
    if (qs == 0) { \
        const unsigned short* sp = Kb + bhbase + (size_t)t64 * 4096 + lohi * 2048 + lane * 8; \
        ld_lds16(sp, dst); ld_lds16(sp + 512, dst + 512); \
        ld_lds16(sp + 1024, dst + 1024); ld_lds16(sp + 1536, dst + 1536); \
    } else { \
        const unsigned short* sp = Vb + bhbase + (size_t)t64 * 4096 + lohi * 1024 + lane * 8; \
        unsigned short* dv = dst + 2048; \
        ld_lds16(sp, dv); ld_lds16(sp + 512, dv + 512); \
        ld_lds16(sp + 2048, dv + 1024); ld_lds16(sp + 2560, dv + 1536); \
    } }
#else
#define STAGE(itx, bb) { \
    const int t64 = kg * 16 + ((itx) >> 1); \
    const int lohi = (itx) & 1; \
    unsigned short* dst = &KV[(bb) * 16384 + kg * 4096]; \
    if (qs == 0) { \
        const unsigned short* sp = Kb + bhbase + (size_t)t64 * 4096 + lohi * 2048 + lane * 8; \
        uint4 a0 = *(const uint4*)(sp); uint4 a1 = *(const uint4*)(sp + 512); \
        uint4 a2 = *(const uint4*)(sp + 1024); uint4 a3 = *(const uint4*)(sp + 1536); \
        *(uint4*)&dst[lane * 8] = a0; *(uint4*)&dst[512 + lane * 8] = a1; \
        *(uint4*)&dst[1024 + lane * 8] = a2; *(uint4*)&dst[1536 + lane * 8] = a3; \
    } else { \
        const unsigned short* sp = Vb + bhbase + (size_t)t64 * 4096 + lohi * 1024 + lane * 8; \
        unsigned short* dv = dst + 2048; \
        uint4 a0 = *(const uint4*)(sp); uint4 a1 = *(const uint4*)(sp + 512); \
        uint4 a2 = *(const uint4*)(sp + 2048); uint4 a3 = *(const uint4*)(sp + 2560); \
        *(uint4*)&dv[lane * 8] = a0; *(uint4*)&dv[512 + lane * 8] = a1; \
        *(uint4*)&dv[1024 + lane * 8] = a2; *(uint4*)&dv[1536 + lane * 8] = a3; \
    } }
#endif

    STAGE(0, 0);

    for (int it = 0; it < 32; ++it) {
        __syncthreads();   // buf[it&1] staged; prev readers of buf[(it+1)&1] done
        const unsigned short* Kbuf = &KV[(it & 1) * 16384 + kg * 4096];
        const unsigned short* Vbuf = Kbuf + 2048;
        if (it < 31) STAGE(it + 1, (it + 1) & 1);

        // QK: one K-frag read feeds both q-tiles' MFMAs (32-key tile)
        f32x16 sa0, sa1;
        {
            f16x8 kf = *(const f16x8*)&Kbuf[0 * 512 + lane * 8];
            sa0 = __builtin_amdgcn_mfma_f32_32x32x16_f16(kf, qf0[0], zf, 0, 0, 0);
            sa1 = __builtin_amdgcn_mfma_f32_32x32x16_f16(kf, qf1[0], zf, 0, 0, 0);
#pragma unroll
            for (int ks = 1; ks < 4; ++ks) {
                kf = *(const f16x8*)&Kbuf[ks * 512 + lane * 8];
                sa0 = __builtin_amdgcn_mfma_f32_32x32x16_f16(kf, qf0[ks], sa0, 0, 0, 0);
                sa1 = __builtin_amdgcn_mfma_f32_32x32x16_f16(kf, qf1[ks], sa1, 0, 0, 0);
            }
        }
        // exp2 fused with f16 pack (16 packed dwords live, not 32 floats)
        unsigned u0[8], u1[8];
        float s0 = 0.f, s1 = 0.f;
#pragma unroll
        for (int j = 0; j < 8; ++j) {
            float ea = __builtin_amdgcn_exp2f(sa0[2 * j]);
            float eb = __builtin_amdgcn_exp2f(sa0[2 * j + 1]);
            s0 += ea + eb;
            u0[j] = pkh(ea, eb);
        }
#pragma unroll
        for (int j = 0; j < 8; ++j) {
            float ea = __builtin_amdgcn_exp2f(sa1[2 * j]);
            float eb = __builtin_amdgcn_exp2f(sa1[2 * j + 1]);
            s1 += ea + eb;
            u1[j] = pkh(ea, eb);
        }
        l0_ += s0; l1_ += s1;

        // PV: one V-frag pair feeds both q-tiles (2 k-slots of 16 keys)
#pragma unroll
        for (int ks2 = 0; ks2 < 2; ++ks2) {
            f16x8 pb0 = xchg2(u0[4 * ks2 + 0], u0[4 * ks2 + 1], u0[4 * ks2 + 2], u0[4 * ks2 + 3], hi);
            f16x8 pb1 = xchg2(u1[4 * ks2 + 0], u1[4 * ks2 + 1], u1[4 * ks2 + 2], u1[4 * ks2 + 3], hi);
            f16x8 va0 = *(const f16x8*)&Vbuf[ks2 * 512 + lane * 8];
            f16x8 va1 = *(const f16x8*)&Vbuf[1024 + ks2 * 512 + lane * 8];
            oacc[0][0] = __builtin_amdgcn_mfma_f32_32x32x16_f16(va0, pb0, oacc[0][0], 0, 0, 0);
            oacc[0][1] = __builtin_amdgcn_mfma_f32_32x32x16_f16(va1, pb0, oacc[0][1], 0, 0, 0);
            oacc[1][0] = __builtin_amdgcn_mfma_f32_32x32x16_f16(va0, pb1, oacc[1][0], 0, 0, 0);
            oacc[1][1] = __builtin_amdgcn_mfma_f32_32x32x16_f16(va1, pb1, oacc[1][1], 0, 0, 0);
        }
    }

    // 4-way kg reduction, 2 phases (one per q-tile t). Per phase: kg1..3 write
    // (6 regions x 2048 floats = 48KB) + l (384 floats); kg0 accumulates.
    __syncthreads();
    float* red = (float*)KV;
#pragma unroll
    for (int t = 0; t < 2; ++t) {
        if (kg != 0) {
            float* rp = red + (qs * 3 + (kg - 1)) * 2048;
#pragma unroll
            for (int dt = 0; dt < 2; ++dt)
#pragma unroll
                for (int g = 0; g < 4; ++g) {
                    float4 v;
                    v.x = oacc[t][dt][g * 4 + 0];
                    v.y = oacc[t][dt][g * 4 + 1];
                    v.z = oacc[t][dt][g * 4 + 2];
                    v.w = oacc[t][dt][g * 4 + 3];
                    *(float4*)&rp[(dt * 4 + g) * 256 + lane * 4] = v;
                }
            red[12288 + (qs * 3 + (kg - 1)) * 64 + lane] = t ? l1_ : l0_;
        }
        __syncthreads();
        if (kg == 0) {
#pragma unroll
            for (int slot = 0; slot < 3; ++slot) {
                float* rp = red + (qs * 3 + slot) * 2048;
#pragma unroll
                for (int dt = 0; dt < 2; ++dt)
#pragma unroll
                    for (int g = 0; g < 4; ++g) {
                        float4 v = *(const float4*)&rp[(dt * 4 + g) * 256 + lane * 4];
                        oacc[t][dt][g * 4 + 0] += v.x;
                        oacc[t][dt][g * 4 + 1] += v.y;
                        oacc[t][dt][g * 4 + 2] += v.z;
                        oacc[t][dt][g * 4 + 3] += v.w;
                    }
                float addl = red[12288 + (qs * 3 + slot) * 64 + lane];
                if (t) l1_ += addl; else l0_ += addl;
            }
        }
        __syncthreads();
    }

    if (kg == 0) {
        l0_ += __shfl_xor(l0_, 32);
        l1_ += __shfl_xor(l1_, 32);
#pragma unroll
        for (int t = 0; t < 2; ++t) {
            const float li = 1.f / (t ? l1_ : l0_);
            const int gm = b * 128 + qt * 4 + qs * 2 + t;
#pragma unroll
            for (int ksg = 0; ksg < 4; ++ksg) {
                const int dt = ksg >> 1, k2 = ksg & 1;
                unsigned g0x = pkh(oacc[t][dt][8 * k2 + 0] * li, oacc[t][dt][8 * k2 + 1] * li);
                unsigned g0y = pkh(oacc[t][dt][8 * k2 + 2] * li, oacc[t][dt][8 * k2 + 3] * li);
                unsigned g1x = pkh(oacc[t][dt][8 * k2 + 4] * li, oacc[t][dt][8 * k2 + 5] * li);
                unsigned g1y = pkh(oacc[t][dt][8 * k2 + 6] * li, oacc[t][dt][8 * k2 + 7] * li);
                f16x8 frag = xchg2(g0x, g0y, g1x, g1y, hi);
                union { f16x8 v; uint4 u; } fu; fu.v = frag;
                *(uint4*)&ObA[((size_t)(gm * 32 + h * 4 + ksg) * 64 + lane) * 8] = fu.u;
            }
        }
    }
}

// ---------- projection GEMM: out = A @ W + b (A,W fragment-ordered f16) ----------
__global__ __launch_bounds__(256) void proj_kernel(
    const unsigned short* __restrict__ ObA,  // [256][32][64][8]
    const unsigned short* __restrict__ Wb,   // [16][32][64][8]
    const float* __restrict__ bias,
    float* __restrict__ out) {
    __shared__ __align__(16) unsigned short Ash[8192];
    __shared__ __align__(16) unsigned short Wsh[4096];

    const int mt = blockIdx.x;
    const int nt = blockIdx.y;
    const int tid = threadIdx.x;
    const int w = tid >> 6;
    const int lane = tid & 63;
    const int q = lane & 31;
    const int hi = lane >> 5;

    f32x16 acc[2];
#pragma unroll
    for (int t = 0; t < 2; ++t)
#pragma unroll
        for (int r = 0; r < 16; ++r) acc[t][r] = 0.f;

    for (int kt = 0; kt < 8; ++kt) {
        __syncthreads();
#pragma unroll
        for (int i = 0; i < 4; ++i) {
            int ci = (tid >> 6) + i * 4;
            int ml = ci >> 2, ksl = ci & 3;
            *(uint4*)&Ash[ci * 512 + lane * 8] =
                *(const uint4*)(ObA + (((size_t)(mt * 4 + ml) * 32 + kt * 4 + ksl) * 64 + lane) * 8);
        }
#pragma unroll
        for (int i = 0; i < 2; ++i) {
            int ci = (tid >> 6) + i * 4;
            int ntl = ci >> 2, ksl = ci & 3;
            *(uint4*)&Wsh[ci * 512 + lane * 8] =
                *(const uint4*)(Wb + (((size_t)(nt * 2 + ntl) * 32 + kt * 4 + ksl) * 64 + lane) * 8);
        }
        __syncthreads();

#pragma unroll
        for (int ks = 0; ks < 4; ++ks) {
            f16x8 a  = *(const f16x8*)&Ash[(w * 4 + ks) * 512 + lane * 8];
            f16x8 b0 = *(const f16x8*)&Wsh[(0 * 4 + ks) * 512 + lane * 8];
            f16x8 b1 = *(const f16x8*)&Wsh[(4 + ks) * 512 + lane * 8];
            acc[0] = __builtin_amdgcn_mfma_f32_32x32x16_f16(a, b0, acc[0], 0, 0, 0);
            acc[1] = __builtin_amdgcn_mfma_f32_32x32x16_f16(a, b1, acc[1], 0, 0, 0);
        }
    }

#pragma unroll
    for (int ntl = 0; ntl < 2; ++ntl) {
        int col = nt * 64 + ntl * 32 + q;
        float bv = bias[col];
#pragma unroll
        for (int reg = 0; reg < 16; ++reg) {
            int row = mt * 128 + w * 32 + (reg & 3) + 8 * (reg >> 2) + 4 * hi;
            out[(size_t)row * Dn + col] = acc[ntl][reg] + bv;
        }
    }
}

extern "C" void kernel_launch(void* const* d_in, const int* in_sizes, int n_in,
                              void* d_out, int out_size, void* d_ws, size_t ws_size,
                              hipStream_t stream) {
    const float* Q = (const float*)d_in[0];
    const float* K = (const float*)d_in[1];
    const float* V = (const float*)d_in[2];
    const float* W = (const float*)d_in[3];
    const float* bo = (const float*)d_in[4];
    float* out = (float*)d_out;

    char* ws = (char*)d_ws;
    unsigned short* Kb  = (unsigned short*)(ws);                 // 8 MB
    unsigned short* Vb  = (unsigned short*)(ws + 8388608);       // 8 MB
    unsigned short* Wb  = (unsigned short*)(ws + 16777216);      // 512 KB
    unsigned short* ObA = (unsigned short*)(ws + 17301504);      // 8 MB

    prep_kernel<<<2176, 256, 0, stream>>>(K, V, W, Kb, Vb, Wb);
    attn_kernel<<<dim3(32, 16), 512, 0, stream>>>(Q, Kb, Vb, ObA);
    proj_kernel<<<dim3(64, 8), 256, 0, stream>>>(ObA, Wb, bo, out);
}

// Round 9
// 188.620 us; speedup vs baseline: 3.4033x; 3.4033x over previous
//
#include <hip/hip_runtime.h>
#include <hip/hip_bf16.h>

#define Bn 2
#define Sn 4096
#define Dn 512
#define Hn 8

typedef _Float16 f16x8 __attribute__((ext_vector_type(8)));
typedef __fp16 fp16x2 __attribute__((ext_vector_type(2)));
typedef float f32x16 __attribute__((ext_vector_type(16)));
typedef unsigned uint2v __attribute__((ext_vector_type(2)));

#if __has_builtin(__builtin_amdgcn_global_load_lds)
#define HAS_GLL 1
typedef const __attribute__((address_space(1))) unsigned int* gas1_t;
typedef __attribute__((address_space(3))) unsigned int* las3_t;
// async 16B/lane global->LDS: LDS dst = uniform base + lane*16
static __device__ __forceinline__ void ld_lds16(const void* g, void* l) {
    __builtin_amdgcn_global_load_lds((gas1_t)g, (las3_t)l, 16, 0, 0);
}
#else
#define HAS_GLL 0
#endif

// pack two f32 -> two f16 in one dword (v_cvt_pkrtz_f16_f32, 1 VALU op)
static __device__ __forceinline__ unsigned pkh(float a, float b) {
    union { fp16x2 h; unsigned u; } r;
    r.h = __builtin_amdgcn_cvt_pkrtz(a, b);
    return r.u;
}

// C-layout group pair -> A/B-fragment (K=16 shapes) via lane^32 exchange.
static __device__ __forceinline__ f16x8 xchg2(unsigned g0x, unsigned g0y,
                                              unsigned g1x, unsigned g1y, int hi) {
    union { unsigned u[4]; f16x8 v; } f;
#if __has_builtin(__builtin_amdgcn_permlane32_swap)
    uint2v rx = __builtin_amdgcn_permlane32_swap(g0x, g1x, false, false);
    uint2v ry = __builtin_amdgcn_permlane32_swap(g0y, g1y, false, false);
    f.u[0] = rx.x; f.u[1] = ry.x; f.u[2] = rx.y; f.u[3] = ry.y;
#else
    int sx = hi ? (int)g0x : (int)g1x;
    int sy = hi ? (int)g0y : (int)g1y;
    int rx = __shfl_xor(sx, 32);
    int ry = __shfl_xor(sy, 32);
    unsigned ox = hi ? g1x : g0x;
    unsigned oy = hi ? g1y : g0y;
    f.u[0] = hi ? (unsigned)rx : ox;
    f.u[1] = hi ? (unsigned)ry : oy;
    f.u[2] = hi ? ox : (unsigned)rx;
    f.u[3] = hi ? oy : (unsigned)ry;
#endif
    return f.v;
}

// ---------- unified prepass: K,V,W fp32 -> fragment-ordered f16 ----------
__global__ __launch_bounds__(256) void prep_kernel(
    const float* __restrict__ K, const float* __restrict__ V, const float* __restrict__ W,
    unsigned short* __restrict__ Kb, unsigned short* __restrict__ Vb,
    unsigned short* __restrict__ Wb) {
    const int vb = blockIdx.x;
    const int tid = threadIdx.x;
    if (vb < 1024) {
        const int kt = vb & 63, bh = vb >> 6;
        const int b = bh >> 3, h = bh & 7;
        unsigned short* dst = Kb + ((size_t)bh * 64 + kt) * 4096;
#pragma unroll
        for (int i = 0; i < 2; ++i) {
            int c = tid + i * 256;
            int f = c >> 6, ln = c & 63;
            int ktile = f >> 2, ks = f & 3;
            int row = ktile * 32 + (ln & 31);
            int dk = ks * 16 + (ln >> 5) * 8;
            const float* src = K + ((size_t)(b * Sn + kt * 64 + row)) * Dn + h * 64 + dk;
            float4 a0 = *(const float4*)src;
            float4 a1 = *(const float4*)(src + 4);
            uint4 o;
            o.x = pkh(a0.x, a0.y); o.y = pkh(a0.z, a0.w);
            o.z = pkh(a1.x, a1.y); o.w = pkh(a1.z, a1.w);
            *(uint4*)(dst + c * 8) = o;
        }
    } else if (vb < 2048) {
        const int u = vb - 1024;
        const int kt = u & 63, bh = u >> 6;
        const int b = bh >> 3, h = bh & 7;
        unsigned short* dst = Vb + ((size_t)bh * 64 + kt) * 4096;
#pragma unroll
        for (int i = 0; i < 2; ++i) {
            int c = tid + i * 256;
            int f = c >> 6, ln = c & 63;
            int dt = f >> 2, ks = f & 3;
            int dk = dt * 32 + (ln & 31);
            int key0 = ks * 16 + (ln >> 5) * 8;
            const float* src = V + ((size_t)(b * Sn + kt * 64 + key0)) * Dn + h * 64 + dk;
            uint4 o;
            o.x = pkh(src[0 * Dn], src[1 * Dn]);
            o.y = pkh(src[2 * Dn], src[3 * Dn]);
            o.z = pkh(src[4 * Dn], src[5 * Dn]);
            o.w = pkh(src[6 * Dn], src[7 * Dn]);
            *(uint4*)(dst + c * 8) = o;
        }
    } else {
        int c = (vb - 2048) * 256 + tid;
        int ln = c & 63, f = c >> 6;
        int ntile = f >> 5, ks = f & 31;
        int n = ntile * 32 + (ln & 31);
        int k0 = ks * 16 + (ln >> 5) * 8;
        uint4 o;
        o.x = pkh(W[(size_t)(k0 + 0) * Dn + n], W[(size_t)(k0 + 1) * Dn + n]);
        o.y = pkh(W[(size_t)(k0 + 2) * Dn + n], W[(size_t)(k0 + 3) * Dn + n]);
        o.z = pkh(W[(size_t)(k0 + 4) * Dn + n], W[(size_t)(k0 + 5) * Dn + n]);
        o.w = pkh(W[(size_t)(k0 + 6) * Dn + n], W[(size_t)(k0 + 7) * Dn + n]);
        *(uint4*)(Wb + c * 8) = o;
    }
}

// ---------- flash attention: 4 waves/SIMD AND 2:1 MFMA:LDS intensity ----------
// R8 geometry, launch-bounds corrected. Empirical hipcc rule (R0/R5/R6/R7/R8
// VGPR ledger): for 512-thr blocks, 2nd arg behaves as blocks/CU ->
// (512,4) capped VGPR at 64 (R8: 1.2GB scratch spill, 551us); (512,2) caps
// at 128 (R6: 72). This identical working set compiled to 116 VGPR in R7 ->
// fits 128 with no spill -> HW schedules 4 waves/SIMD; LDS 64KB -> 2 blk/CU
// -> 16 waves/CU. First config with both proven levers: R0's occupancy AND
// R7's 2:1 intensity. 512 thr = 8 waves = (qs 0..1 q-sub64) x (kg 0..3 key
// quarter); wave = 64 q-rows x 1024 keys, 32 iters x 32-key tiles, 16 MFMA /
// 8KB LDS per iter. In-block kg-reduction (2-phase LDS epilogue). XCD swizzle:
// 2 bh/XCD -> Kb+Vb 2MB L2-resident.
__global__ __launch_bounds__(512, 2) void attn_kernel(
    const float* __restrict__ Q,
    const unsigned short* __restrict__ Kb,
    const unsigned short* __restrict__ Vb,
    unsigned short* __restrict__ ObA) {   // [gmtile 256][ksg 32][lane 64][8]
    // main: [buf 2][kg 4][ K 4 frags | V dt0 2 | V dt1 2 ] = 2*4*4096 ush = 64KB
    // epilogue reuse: 12288 floats oacc partials + 384 floats l = 50688B
    __shared__ __align__(16) unsigned short KV[32768];

    // XCD-aware remap: id%8 = XCD (round-robin dispatch); same-bh blocks on one XCD
    const int id = blockIdx.x + (blockIdx.y << 5);
    const int qt = (id >> 3) & 31;
    const int bh = (id & 7) + ((id >> 8) << 3);
    const int b = bh >> 3, h = bh & 7;
    const int tid = threadIdx.x;
    const int wg = tid >> 6;
    const int kg = wg >> 1;        // key quarter 0..3
    const int qs = wg & 1;         // q-subgroup + staging role (0:K, 1:V)
    const int lane = tid & 63;
    const int q = lane & 31;
    const int hi = lane >> 5;
    const float cexp = 0.18033688f;  // (1/sqrt(64)) * log2(e), folded into Q

    // Q B-frags for two q-tiles: rows qt*128 + qs*64 + t*32 + q
    f16x8 qf0[4], qf1[4];
    {
        const float* qp0 = Q + ((size_t)(b * Sn + qt * 128 + qs * 64 + q)) * Dn + h * 64 + hi * 8;
        const float* qp1 = qp0 + (size_t)32 * Dn;
#pragma unroll
        for (int ks = 0; ks < 4; ++ks) {
            float4 a0 = *(const float4*)(qp0 + ks * 16);
            float4 a1 = *(const float4*)(qp0 + ks * 16 + 4);
            union { unsigned u[4]; f16x8 v; } f;
            f.u[0] = pkh(a0.x * cexp, a0.y * cexp);
            f.u[1] = pkh(a0.z * cexp, a0.w * cexp);
            f.u[2] = pkh(a1.x * cexp, a1.y * cexp);
            f.u[3] = pkh(a1.z * cexp, a1.w * cexp);
            qf0[ks] = f.v;
            a0 = *(const float4*)(qp1 + ks * 16);
            a1 = *(const float4*)(qp1 + ks * 16 + 4);
            f.u[0] = pkh(a0.x * cexp, a0.y * cexp);
            f.u[1] = pkh(a0.z * cexp, a0.w * cexp);
            f.u[2] = pkh(a1.x * cexp, a1.y * cexp);
            f.u[3] = pkh(a1.z * cexp, a1.w * cexp);
            qf1[ks] = f.v;
        }
    }

    f32x16 zf;
#pragma unroll
    for (int r = 0; r < 16; ++r) zf[r] = 0.f;
    f32x16 oacc[2][2];  // [q-tile t][d-tile dt]
    oacc[0][0] = zf; oacc[0][1] = zf; oacc[1][0] = zf; oacc[1][1] = zf;
    float l0_ = 0.f, l1_ = 0.f;

    const size_t bhbase = (size_t)bh * 64 * 4096;  // ushorts: 64 tiles x 8 frags x 512

    // stream kg, iter it covers keys kg*1024 + it*32 .. +31:
    // prep tile t64 = kg*16 + (it>>1); lo/hi half = it&1.
    // K frags (32 keys): t64 frags lohi*4 .. +3 (contiguous 4KB).
    // V frags: dt0 -> {lohi*2, lohi*2+1}, dt1 -> {4+lohi*2, 4+lohi*2+1}.
#if HAS_GLL
#define STAGE(itx, bb) { \
    const int t64 = kg * 16 + ((itx) >> 1); \
    const int lohi = (itx) & 1; \
    unsigned short* dst = &KV[(bb) * 16384 + kg * 4096]; \
    if (qs == 0) { \
        const unsigned short* sp = Kb + bhbase + (size_t)t64 * 4096 + lohi * 2048 + lane * 8; \
        ld_lds16(sp, dst); ld_lds16(sp + 512, dst + 512); \
        ld_lds16(sp + 1024, dst + 1024); ld_lds16(sp + 1536, dst + 1536); \
    } else { \
        const unsigned short* sp = Vb + bhbase + (size_t)t64 * 4096 + lohi * 1024 + lane * 8; \
        unsigned short* dv = dst + 2048; \
        ld_lds16(sp, dv); ld_lds16(sp + 512, dv + 512); \
        ld_lds16(sp + 2048, dv + 1024); ld_lds16(sp + 2560, dv + 1536); \
    } }
#else
#define STAGE(itx, bb) { \
    const int t64 = kg * 16 + ((itx) >> 1); \
    const int lohi = (itx) & 1; \
    unsigned short* dst = &KV[(bb) * 16384 + kg * 4096]; \
    if (qs == 0) { \
        const unsigned short* sp = Kb + bhbase + (size_t)t64 * 4096 + lohi * 2048 + lane * 8; \
        uint4 a0 = *(const uint4*)(sp); uint4 a1 = *(const uint4*)(sp + 512); \
        uint4 a2 = *(const uint4*)(sp + 1024); uint4 a3 = *(const uint4*)(sp + 1536); \
        *(uint4*)&dst[lane * 8] = a0; *(uint4*)&dst[512 + lane * 8] = a1; \
        *(uint4*)&dst[1024 + lane * 8] = a2; *(uint4*)&dst[1536 + lane * 8] = a3; \
    } else { \
        const unsigned short* sp = Vb + bhbase + (size_t)t64 * 4096 + lohi * 1024 + lane * 8; \
        unsigned short* dv = dst + 2048; \
        uint4 a0 = *(const uint4*)(sp); uint4 a1 = *(const uint4*)(sp + 512); \
        uint4 a2 = *(const uint4*)(sp + 2048); uint4 a3 = *(const uint4*)(sp + 2560); \
        *(uint4*)&dv[lane * 8] = a0; *(uint4*)&dv[512 + lane * 8] = a1; \
        *(uint4*)&dv[1024 + lane * 8] = a2; *(uint4*)&dv[1536 + lane * 8] = a3; \
    } }
#endif

    STAGE(0, 0);

    for (int it = 0; it < 32; ++it) {
        __syncthreads();   // buf[it&1] staged; prev readers of buf[(it+1)&1] done
        const unsigned short* Kbuf = &KV[(it & 1) * 16384 + kg * 4096];
        const unsigned short* Vbuf = Kbuf + 2048;
        if (it < 31) STAGE(it + 1, (it + 1) & 1);

        // QK: one K-frag read feeds both q-tiles' MFMAs (32-key tile)
        f32x16 sa0, sa1;
        {
            f16x8 kf = *(const f16x8*)&Kbuf[0 * 512 + lane * 8];
            sa0 = __builtin_amdgcn_mfma_f32_32x32x16_f16(kf, qf0[0], zf, 0, 0, 0);
            sa1 = __builtin_amdgcn_mfma_f32_32x32x16_f16(kf, qf1[0], zf, 0, 0, 0);
#pragma unroll
            for (int ks = 1; ks < 4; ++ks) {
                kf = *(const f16x8*)&Kbuf[ks * 512 + lane * 8];
                sa0 = __builtin_amdgcn_mfma_f32_32x32x16_f16(kf, qf0[ks], sa0, 0, 0, 0);
                sa1 = __builtin_amdgcn_mfma_f32_32x32x16_f16(kf, qf1[ks], sa1, 0, 0, 0);
            }
        }
        // exp2 fused with f16 pack (16 packed dwords live, not 32 floats)
        unsigned u0[8], u1[8];
        float s0 = 0.f, s1 = 0.f;
#pragma unroll
        for (int j = 0; j < 8; ++j) {
            float ea = __builtin_amdgcn_exp2f(sa0[2 * j]);
            float eb = __builtin_amdgcn_exp2f(sa0[2 * j + 1]);
            s0 += ea + eb;
            u0[j] = pkh(ea, eb);
        }
#pragma unroll
        for (int j = 0; j < 8; ++j) {
            float ea = __builtin_amdgcn_exp2f(sa1[2 * j]);
            float eb = __builtin_amdgcn_exp2f(sa1[2 * j + 1]);
            s1 += ea + eb;
            u1[j] = pkh(ea, eb);
        }
        l0_ += s0; l1_ += s1;

        // PV: one V-frag pair feeds both q-tiles (2 k-slots of 16 keys)
#pragma unroll
        for (int ks2 = 0; ks2 < 2; ++ks2) {
            f16x8 pb0 = xchg2(u0[4 * ks2 + 0], u0[4 * ks2 + 1], u0[4 * ks2 + 2], u0[4 * ks2 + 3], hi);
            f16x8 pb1 = xchg2(u1[4 * ks2 + 0], u1[4 * ks2 + 1], u1[4 * ks2 + 2], u1[4 * ks2 + 3], hi);
            f16x8 va0 = *(const f16x8*)&Vbuf[ks2 * 512 + lane * 8];
            f16x8 va1 = *(const f16x8*)&Vbuf[1024 + ks2 * 512 + lane * 8];
            oacc[0][0] = __builtin_amdgcn_mfma_f32_32x32x16_f16(va0, pb0, oacc[0][0], 0, 0, 0);
            oacc[0][1] = __builtin_amdgcn_mfma_f32_32x32x16_f16(va1, pb0, oacc[0][1], 0, 0, 0);
            oacc[1][0] = __builtin_amdgcn_mfma_f32_32x32x16_f16(va0, pb1, oacc[1][0], 0, 0, 0);
            oacc[1][1] = __builtin_amdgcn_mfma_f32_32x32x16_f16(va1, pb1, oacc[1][1], 0, 0, 0);
        }
    }

    // 4-way kg reduction, 2 phases (one per q-tile t). Per phase: kg1..3 write
    // (6 regions x 2048 floats = 48KB) + l (384 floats); kg0 accumulates.
    __syncthreads();
    float* red = (float*)KV;
#pragma unroll
    for (int t = 0; t < 2; ++t) {
        if (kg != 0) {
            float* rp = red + (qs * 3 + (kg - 1)) * 2048;
#pragma unroll
            for (int dt = 0; dt < 2; ++dt)
#pragma unroll
                for (int g = 0; g < 4; ++g) {
                    float4 v;
                    v.x = oacc[t][dt][g * 4 + 0];
                    v.y = oacc[t][dt][g * 4 + 1];
                    v.z = oacc[t][dt][g * 4 + 2];
                    v.w = oacc[t][dt][g * 4 + 3];
                    *(float4*)&rp[(dt * 4 + g) * 256 + lane * 4] = v;
                }
            red[12288 + (qs * 3 + (kg - 1)) * 64 + lane] = t ? l1_ : l0_;
        }
        __syncthreads();
        if (kg == 0) {
#pragma unroll
            for (int slot = 0; slot < 3; ++slot) {
                float* rp = red + (qs * 3 + slot) * 2048;
#pragma unroll
                for (int dt = 0; dt < 2; ++dt)
#pragma unroll
                    for (int g = 0; g < 4; ++g) {
                        float4 v = *(const float4*)&rp[(dt * 4 + g) * 256 + lane * 4];
                        oacc[t][dt][g * 4 + 0] += v.x;
                        oacc[t][dt][g * 4 + 1] += v.y;
                        oacc[t][dt][g * 4 + 2] += v.z;
                        oacc[t][dt][g * 4 + 3] += v.w;
                    }
                float addl = red[12288 + (qs * 3 + slot) * 64 + lane];
                if (t) l1_ += addl; else l0_ += addl;
            }
        }
        __syncthreads();
    }

    if (kg == 0) {
        l0_ += __shfl_xor(l0_, 32);
        l1_ += __shfl_xor(l1_, 32);
#pragma unroll
        for (int t = 0; t < 2; ++t) {
            const float li = 1.f / (t ? l1_ : l0_);
            const int gm = b * 128 + qt * 4 + qs * 2 + t;
#pragma unroll
            for (int ksg = 0; ksg < 4; ++ksg) {
                const int dt = ksg >> 1, k2 = ksg & 1;
                unsigned g0x = pkh(oacc[t][dt][8 * k2 + 0] * li, oacc[t][dt][8 * k2 + 1] * li);
                unsigned g0y = pkh(oacc[t][dt][8 * k2 + 2] * li, oacc[t][dt][8 * k2 + 3] * li);
                unsigned g1x = pkh(oacc[t][dt][8 * k2 + 4] * li, oacc[t][dt][8 * k2 + 5] * li);
                unsigned g1y = pkh(oacc[t][dt][8 * k2 + 6] * li, oacc[t][dt][8 * k2 + 7] * li);
                f16x8 frag = xchg2(g0x, g0y, g1x, g1y, hi);
                union { f16x8 v; uint4 u; } fu; fu.v = frag;
                *(uint4*)&ObA[((size_t)(gm * 32 + h * 4 + ksg) * 64 + lane) * 8] = fu.u;
            }
        }
    }
}

// ---------- projection GEMM: out = A @ W + b (A,W fragment-ordered f16) ----------
__global__ __launch_bounds__(256) void proj_kernel(
    const unsigned short* __restrict__ ObA,  // [256][32][64][8]
    const unsigned short* __restrict__ Wb,   // [16][32][64][8]
    const float* __restrict__ bias,
    float* __restrict__ out) {
    __shared__ __align__(16) unsigned short Ash[8192];
    __shared__ __align__(16) unsigned short Wsh[4096];

    const int mt = blockIdx.x;
    const int nt = blockIdx.y;
    const int tid = threadIdx.x;
    const int w = tid >> 6;
    const int lane = tid & 63;
    const int q = lane & 31;
    const int hi = lane >> 5;

    f32x16 acc[2];
#pragma unroll
    for (int t = 0; t < 2; ++t)
#pragma unroll
        for (int r = 0; r < 16; ++r) acc[t][r] = 0.f;

    for (int kt = 0; kt < 8; ++kt) {
        __syncthreads();
#pragma unroll
        for (int i = 0; i < 4; ++i) {
            int ci = (tid >> 6) + i * 4;
            int ml = ci >> 2, ksl = ci & 3;
            *(uint4*)&Ash[ci * 512 + lane * 8] =
                *(const uint4*)(ObA + (((size_t)(mt * 4 + ml) * 32 + kt * 4 + ksl) * 64 + lane) * 8);
        }
#pragma unroll
        for (int i = 0; i < 2; ++i) {
            int ci = (tid >> 6) + i * 4;
            int ntl = ci >> 2, ksl = ci & 3;
            *(uint4*)&Wsh[ci * 512 + lane * 8] =
                *(const uint4*)(Wb + (((size_t)(nt * 2 + ntl) * 32 + kt * 4 + ksl) * 64 + lane) * 8);
        }
        __syncthreads();

#pragma unroll
        for (int ks = 0; ks < 4; ++ks) {
            f16x8 a  = *(const f16x8*)&Ash[(w * 4 + ks) * 512 + lane * 8];
            f16x8 b0 = *(const f16x8*)&Wsh[(0 * 4 + ks) * 512 + lane * 8];
            f16x8 b1 = *(const f16x8*)&Wsh[(4 + ks) * 512 + lane * 8];
            acc[0] = __builtin_amdgcn_mfma_f32_32x32x16_f16(a, b0, acc[0], 0, 0, 0);
            acc[1] = __builtin_amdgcn_mfma_f32_32x32x16_f16(a, b1, acc[1], 0, 0, 0);
        }
    }

#pragma unroll
    for (int ntl = 0; ntl < 2; ++ntl) {
        int col = nt * 64 + ntl * 32 + q;
        float bv = bias[col];
#pragma unroll
        for (int reg = 0; reg < 16; ++reg) {
            int row = mt * 128 + w * 32 + (reg & 3) + 8 * (reg >> 2) + 4 * hi;
            out[(size_t)row * Dn + col] = acc[ntl][reg] + bv;
        }
    }
}

extern "C" void kernel_launch(void* const* d_in, const int* in_sizes, int n_in,
                              void* d_out, int out_size, void* d_ws, size_t ws_size,
                              hipStream_t stream) {
    const float* Q = (const float*)d_in[0];
    const float* K = (const float*)d_in[1];
    const float* V = (const float*)d_in[2];
    const float* W = (const float*)d_in[3];
    const float* bo = (const float*)d_in[4];
    float* out = (float*)d_out;

    char* ws = (char*)d_ws;
    unsigned short* Kb  = (unsigned short*)(ws);                 // 8 MB
    unsigned short* Vb  = (unsigned short*)(ws + 8388608);       // 8 MB
    unsigned short* Wb  = (unsigned short*)(ws + 16777216);      // 512 KB
    unsigned short* ObA = (unsigned short*)(ws + 17301504);      // 8 MB

    prep_kernel<<<2176, 256, 0, stream>>>(K, V, W, Kb, Vb, Wb);
    attn_kernel<<<dim3(32, 16), 512, 0, stream>>>(Q, Kb, Vb, ObA);
    proj_kernel<<<dim3(64, 8), 256, 0, stream>>>(ObA, Wb, bo, out);
}